// Round 9
// baseline (168.036 us; speedup 1.0000x reference)
//
#include <hip/hip_runtime.h>

// All-pole IIR: y[t] = x[t] - sum_{k=1..16} a_k y[t-k], zero initial state.
// Chunked warm-up + block LDS staging (x fetched once) + full-line stores.
// R9: halve redundancy. L 64->128 (redundancy (W+L)/L: 6x -> 3.5x, VALU
// work -42%) with BLOCK 256->128 so the LDS window is unchanged (16704
// floats, 2 blocks/CU). Occupancy drops to 1 wave/SIMD; covered by R7's
// proven 4-chain tree STEP (ILP) + distance-2 triple-buffer prefetch.
// Pad is now u + (u>>5): lane stride 33 units == R7's measured-0-conflict
// start-bank pattern (4*lane mod 32); >>4 at this stride would use only
// half the banks. Serial-chain STEP (R8) is reverted - it stalled.

constexpr int B_ = 32;
constexpr int C_ = 8;
constexpr int T_ = 65536;
constexpr int P_ = 16;
constexpr int BC = B_ * C_;              // 256 channels
constexpr int L_ = 128;                  // outputs per thread
constexpr int W_ = 320;                  // warm-up samples
constexpr int NCHUNK = T_ / L_;          // 512
constexpr int BLOCK = 128;
constexpr int CHUNKS_PER_BLK = BLOCK;    // 128
constexpr int BLKS_PER_CH = NCHUNK / CHUNKS_PER_BLK;  // 4
constexpr int NBLOCKS = BC * BLKS_PER_CH;             // 1024
constexpr int NSTAGE = CHUNKS_PER_BLK * L_ + W_;      // 16704 floats
constexpr int NUNITS = NSTAGE / 4;       // 4176 16B-units
constexpr int NUNITS_PAD = NUNITS + (NUNITS >> 5) + 1;  // 4307 units = 68912B

__device__ __forceinline__ float f4c(const float4& v, int c) {
    switch (c & 3) {
        case 0:  return v.x;
        case 1:  return v.y;
        case 2:  return v.z;
        default: return v.w;
    }
}

// 16 recurrence steps from float4 P[4]. R7 tree: 4 parallel partial chains
// per step (ILP ~4), only cross-step dep is the final b1 fma.
#define STEPB(P)                                                          \
    _Pragma("unroll")                                                     \
    for (int s = 0; s < 16; ++s) {                                        \
        float c0 = fmaf(b[2],  h[(s - 2)  & 15], f4c((P)[s >> 2], s));    \
        c0 = fmaf(b[3],  h[(s - 3)  & 15], c0);                           \
        c0 = fmaf(b[4],  h[(s - 4)  & 15], c0);                           \
        c0 = fmaf(b[5],  h[(s - 5)  & 15], c0);                           \
        float c1 = b[6] * h[(s - 6)  & 15];                               \
        c1 = fmaf(b[7],  h[(s - 7)  & 15], c1);                           \
        c1 = fmaf(b[8],  h[(s - 8)  & 15], c1);                           \
        c1 = fmaf(b[9],  h[(s - 9)  & 15], c1);                           \
        float c2 = b[10] * h[(s - 10) & 15];                              \
        c2 = fmaf(b[11], h[(s - 11) & 15], c2);                           \
        c2 = fmaf(b[12], h[(s - 12) & 15], c2);                           \
        c2 = fmaf(b[13], h[(s - 13) & 15], c2);                           \
        float c3 = b[14] * h[(s - 14) & 15];                              \
        c3 = fmaf(b[15], h[(s - 15) & 15], c3);                           \
        c3 = fmaf(b[16], h[(s - 16) & 15], c3);                           \
        const float pre = (c0 + c1) + (c2 + c3);                          \
        h[s] = fmaf(b[1], h[(s - 1) & 15], pre);                          \
    }

#define STEPO(P, OS)                                                      \
    _Pragma("unroll")                                                     \
    for (int s = 0; s < 16; ++s) {                                        \
        float c0 = fmaf(b[2],  h[(s - 2)  & 15], f4c((P)[s >> 2], s));    \
        c0 = fmaf(b[3],  h[(s - 3)  & 15], c0);                           \
        c0 = fmaf(b[4],  h[(s - 4)  & 15], c0);                           \
        c0 = fmaf(b[5],  h[(s - 5)  & 15], c0);                           \
        float c1 = b[6] * h[(s - 6)  & 15];                               \
        c1 = fmaf(b[7],  h[(s - 7)  & 15], c1);                           \
        c1 = fmaf(b[8],  h[(s - 8)  & 15], c1);                           \
        c1 = fmaf(b[9],  h[(s - 9)  & 15], c1);                           \
        float c2 = b[10] * h[(s - 10) & 15];                              \
        c2 = fmaf(b[11], h[(s - 11) & 15], c2);                           \
        c2 = fmaf(b[12], h[(s - 12) & 15], c2);                           \
        c2 = fmaf(b[13], h[(s - 13) & 15], c2);                           \
        float c3 = b[14] * h[(s - 14) & 15];                              \
        c3 = fmaf(b[15], h[(s - 15) & 15], c3);                           \
        c3 = fmaf(b[16], h[(s - 16) & 15], c3);                           \
        const float pre = (c0 + c1) + (c2 + c3);                          \
        h[s] = fmaf(b[1], h[(s - 1) & 15], pre);                          \
        (OS)[s] = h[s];                                                   \
    }

// Read iter i's 16 floats: raw units ru = 32*tid + 4*i (L=128 -> 32
// units/thread); padded pu = ru + (ru>>5): the 4 units stay CONSECUTIVE
// (4i..4i+3 never straddles a 32-boundary).
#define LDSRD(P, i) do {                                                  \
        const int ru_ = (tid << 5) + ((i) << 2);                          \
        const int pu_ = ru_ + (ru_ >> 5);                                 \
        (P)[0] = lds4[pu_ + 0]; (P)[1] = lds4[pu_ + 1];                   \
        (P)[2] = lds4[pu_ + 2]; (P)[3] = lds4[pu_ + 3];                   \
    } while (0)

#define STORE16(OFS, SRC) do {                                            \
        _Pragma("unroll")                                                 \
        for (int q = 0; q < 4; ++q) {                                     \
            float4 v;                                                     \
            v.x = (SRC)[q * 4 + 0]; v.y = (SRC)[q * 4 + 1];               \
            v.z = (SRC)[q * 4 + 2]; v.w = (SRC)[q * 4 + 3];               \
            *reinterpret_cast<float4*>(yc + obase + (OFS) + q * 4) = v;   \
        }                                                                 \
    } while (0)

__global__ __launch_bounds__(BLOCK, 1) void allpole_kernel(
    const float* __restrict__ x, const float* __restrict__ a,
    float* __restrict__ y)
{
    __shared__ float4 lds4[NUNITS_PAD];  // 68912 B; 2 blocks/CU

    const int tid = threadIdx.x;
    const int blk = blockIdx.x;
    const int ch  = blk >> 2;                        // / BLKS_PER_CH
    const int ci0 = (blk & (BLKS_PER_CH - 1)) * CHUNKS_PER_BLK;
    const int ci  = ci0 + tid;

    const float* __restrict__ xc = x + (size_t)ch * T_;
    float* __restrict__ yc       = y + (size_t)ch * T_;
    const float* __restrict__ ac = a + ch * (P_ + 1);

    // ---- Stage x window into padded LDS (zeros materialized for t<0) ----
    const int xbase = ci0 * L_ - W_;
    for (int u = tid; u < NUNITS; u += BLOCK) {
        const int af = xbase + u * 4;
        float4 v;
        if (af >= 0) v = *reinterpret_cast<const float4*>(xc + af);
        else { v.x = 0.0f; v.y = 0.0f; v.z = 0.0f; v.w = 0.0f; }
        lds4[u + (u >> 5)] = v;
    }

    const float inv_a0 = 1.0f / ac[0];
    float b[P_ + 1];
#pragma unroll
    for (int k = 1; k <= P_; ++k) b[k] = -ac[k] * inv_a0;

    float h[16];
#pragma unroll
    for (int i = 0; i < 16; ++i) h[i] = 0.0f;

    __syncthreads();

    float4 pA[4], pB[4], pC[4];
    LDSRD(pA, 0);
    LDSRD(pB, 1);

    // ---- Phase A: warm-up iters 0..19 (rolled x3 + tail), distance-2 ----
#pragma unroll 1
    for (int it = 0; it < 18; it += 3) {
        LDSRD(pC, it + 2);  STEPB(pA)
        LDSRD(pA, it + 3);  STEPB(pB)
        LDSRD(pB, it + 4);  STEPB(pC)
    }
    LDSRD(pC, 20);  STEPB(pA)            // iter 18
    LDSRD(pA, 21);  STEPB(pB)            // iter 19

    // ---- Phase B: output iters 20..27 -> four full 128B lines ----
    const int obase = ci * L_;
    float os[16];

    LDSRD(pB, 22);  STEPO(pC, os)        // iter 20
    LDSRD(pC, 23);  STEPB(pA)            // iter 21
    STORE16(0, os); STORE16(16, h);

    LDSRD(pA, 24);  STEPO(pB, os)        // iter 22
    LDSRD(pB, 25);  STEPB(pC)            // iter 23
    STORE16(32, os); STORE16(48, h);

    LDSRD(pC, 26);  STEPO(pA, os)        // iter 24
    LDSRD(pA, 27);  STEPB(pB)            // iter 25
    STORE16(64, os); STORE16(80, h);

    STEPO(pC, os)                        // iter 26
    STEPB(pA)                            // iter 27
    STORE16(96, os); STORE16(112, h);
}

extern "C" void kernel_launch(void* const* d_in, const int* in_sizes, int n_in,
                              void* d_out, int out_size, void* d_ws, size_t ws_size,
                              hipStream_t stream) {
    const float* x = (const float*)d_in[0];
    const float* a = (const float*)d_in[1];
    float* y = (float*)d_out;
    allpole_kernel<<<NBLOCKS, BLOCK, 0, stream>>>(x, a, y);
}